// Round 6
// baseline (278.571 us; speedup 1.0000x reference)
//
#include <hip/hip_runtime.h>
#include <hip/hip_cooperative_groups.h>
#include <cstdint>

namespace cg = cooperative_groups;

typedef unsigned long long u64;
typedef unsigned int u32;

#define B_ 4
#define N_ 3600
#define C_ 16
#define NW_ 57        // ceil(N/64) words of adjacency/valid bitmask
#define NPAD_ 3648    // NW_*64
#define RPW_ 2        // rows per wave (adj phase, 8 waves -> 16 rows/unit)
#define RPB_ 16       // rows per unit (adj phase)
#define NUNITS_ (B_ * N_ / RPB_)   // 900
#define TPI_ 1596     // transpose tiles per image: 57*56/2
#define HW0_ 1856     // j-half 0: words 0..28  (29 words)
#define HW1_ 1792     // j-half 1: words 29..56 (28 words)
#define CH_ 64        // greedy chunk size (candidates per resolution round)
#define NT_ 512       // threads per block
#define NWV_ 8        // waves per block
#define RPWG_ 8       // rows per wave in greedy phases (CH_/NWV_)
#define GRID_ 256     // cooperative grid (1 block/CU, LDS-limited)

// ---------------------------------------------------------------------------
// Single cooperative mega-kernel. Rationale: cross-round accounting showed
// kernel times never sum to dur_us — ~15-18 us per dispatch boundary, ~50 us
// across the 4-kernel pipeline. 3 grid.sync()s (~2-3 us each) replace them.
// Phases:
//  0: zero out[] + cnt[] (grid-stride; absorbs the old memset/full-slice
//     writes — nms then writes only survivors).
//  1: adjacency, UPPER-TRIANGLE only (IoU exactly symmetric: fmin/fmax/
//     add/mul commutative -> bit(i,j)==bit(j,i)). 900 units of 16 rows,
//     grid-stride; LDS-staged j-range in two halves (proven R2 structure).
//     Exact division-free IoU: round_f32(inter/denom) >= 0.4f  <=>
//     inter > (0.4f - 2^-26)*denom in f64 (26x24-bit product exact;
//     midpoint ties round-to-even below 0.4f -> false, matching strict '>';
//     denom==0 => inter==0 => false = reference NaN>=0.4). Diagonal cleared
//     post-hoc (word w0 wave-uniform).
//  2: mirror lower triangle: one wave per 64x64 bit tile (wi>wj), classic
//     6-step shfl_xor block-swap bit-transpose.
//  3: acon + candidate emission: one wave per row; sparse con gather +
//     6-step shuffle max-reduce; lane 0 evaluates
//     valid0 = (p>=conf_c) && (p>=fmax(adj_con,con_c)) (exact: p>=a && p>=b
//     <=> p>=fmax(a,b), non-NaN; adj_con init 0 matches where(adj,con,0)
//     and subsumes p>=0) and emits sort key (~pk)<<32|i via atomicAdd.
//     Arrival order nondeterministic; keys unique -> sort is deterministic.
//  4: blocks 0..63: per-(b,c) sort + greedy + output.
//     - rank sort via readlane broadcasts (keys padded with ~0ull).
//     - chunk-parallel greedy; in-chunk resolve by PARALLEL PEELING
//       (replaces ~59 serial dependent steps/chunk): round-accept every
//       candidate with no earlier UNDECIDED neighbor; strike accepted
//       rows' neighbors (OR-reduce via shfl_xor). Accept rule == lexico-
//       graphically-first MIS == sequential greedy: earlier neighbor
//       accepted => r already struck; rejected => doesn't block; undecided
//       => wait. Lowest bit of cv always qualifies => >=1 accept/round.
//     Survivor order == greedy order == reference order; suppressed rows
//     stay exact zeros (pre-zeroed in phase 0).
// ---------------------------------------------------------------------------
union SMem {
    float4 sbox[HW0_];                       // phase 1 (29.7 KB)
    struct {
        union {
            u64 keys[NPAD_];                 // sort (29.2 KB)
            u64 srows[2][CH_][NW_];          // greedy (58.4 KB)
        } ov;
        u32 sidx[NPAD_];
        float sscore[NPAD_];
        u32 slist[NPAD_];
        float slistf[NPAD_];
        u64 sintra[CH_];
        u64 vmask[NW_];
        u64 s_accept;
        u32 s_S;
    } nms;                                   // phase 4 (117.7 KB)
};

__global__ void __launch_bounds__(NT_) k_all(const float* __restrict__ pro,
                                             const float* __restrict__ con,
                                             const float* __restrict__ boxes,
                                             const float* __restrict__ scales,
                                             const float* __restrict__ conf,
                                             u64* __restrict__ adj,
                                             u64* __restrict__ cand,
                                             u32* __restrict__ cnt,
                                             float* __restrict__ out,
                                             int nout) {
#pragma clang fp contract(off)
    __shared__ SMem sm;
    cg::grid_group grid = cg::this_grid();
    const int tid  = threadIdx.x;
    const int lane = tid & 63;
    const int wv   = tid >> 6;
    const int bid  = blockIdx.x;
    const double MID = (double)0.4f - 0x1p-26;   // exact

    // ---- phase 0: zero out + cnt ----
    {
        float4* o4 = reinterpret_cast<float4*>(out);
        const int n4 = nout >> 2;
        const float4 z = make_float4(0.f, 0.f, 0.f, 0.f);
        for (int x = bid * NT_ + tid; x < n4; x += GRID_ * NT_) o4[x] = z;
        if (bid == 0)
            for (int x = tid; x < B_ * C_ * 16; x += NT_) cnt[x] = 0;
    }

    // ---- phase 1: adjacency (upper triangle) ----
    for (int u = bid; u < NUNITS_; u += GRID_) {
        const int b  = u / (N_ / RPB_);
        const int rg = u % (N_ / RPB_);
        const int r0 = rg * RPB_ + wv * RPW_;
        const int w0 = rg >> 2;                  // first word (unit-uniform)
        const size_t bN = (size_t)b * N_;

        float4 bi[RPW_];
        float  ai[RPW_];
#pragma unroll
        for (int r = 0; r < RPW_; ++r) {
            const float4 bx = reinterpret_cast<const float4*>(boxes)[bN + r0 + r];
            const float x1 = bx.x - bx.z * 0.5f;   // reference op order
            const float y1 = bx.y - bx.w * 0.5f;
            const float x2 = x1 + bx.z;
            const float y2 = y1 + bx.w;
            bi[r] = make_float4(x1, y1, x2, y2);
            ai[r] = (x2 - x1) * (y2 - y1);
        }

        u64 row[RPW_];
#pragma unroll
        for (int r = 0; r < RPW_; ++r) row[r] = 0ull;

        int jbase = 0;
        for (int h = 0; h < 2; ++h) {
            const int cnt_h = h ? HW1_ : HW0_;
            const int wlo   = jbase >> 6;
            const int wcnt  = cnt_h >> 6;
            if (w0 < wlo + wcnt) {               // unit-uniform skip
                const int tw0 = max(w0 - wlo, 0);
                const int jj0 = tw0 << 6;
                __syncthreads();                 // protect previous reads
                for (int jj = jj0 + tid; jj < cnt_h; jj += NT_) {
                    const int j = jbase + jj;
                    float x1 = 0.f, y1 = 0.f, x2 = 0.f, y2 = 0.f;
                    if (j < N_) {
                        const float4 bx =
                            reinterpret_cast<const float4*>(boxes)[bN + j];
                        x1 = bx.x - bx.z * 0.5f;
                        y1 = bx.y - bx.w * 0.5f;
                        x2 = x1 + bx.z;
                        y2 = y1 + bx.w;
                    }
                    sm.sbox[jj] = make_float4(x1, y1, x2, y2);
                }
                __syncthreads();

                for (int tw = tw0; tw < wcnt; ++tw) {
                    const int tglob = wlo + tw;
                    const float4 bj = sm.sbox[tw * 64 + lane];
                    const float ajr = (bj.z - bj.x) * (bj.w - bj.y);
#pragma unroll
                    for (int r = 0; r < RPW_; ++r) {
                        const float ltx = fmaxf(bi[r].x, bj.x);
                        const float lty = fmaxf(bi[r].y, bj.y);
                        const float rbx = fminf(bi[r].z, bj.z);
                        const float rby = fminf(bi[r].w, bj.w);
                        const float whx = fmaxf(rbx - ltx, 0.0f);
                        const float why = fmaxf(rby - lty, 0.0f);
                        const float inter = whx * why;
                        const float denom = (ai[r] + ajr) - inter;
                        const int pred = ((double)inter > MID * (double)denom);
                        const u64 m = __ballot(pred);
                        if (lane == tglob) row[r] = m;
                    }
                }
            }
            jbase += cnt_h;
        }

#pragma unroll
        for (int r = 0; r < RPW_; ++r)
            if (lane == w0) row[r] &= ~(1ull << ((r0 + r) & 63));
#pragma unroll
        for (int r = 0; r < RPW_; ++r)
            if (lane >= w0 && lane < NW_)
                adj[(bN + r0 + r) * (size_t)NW_ + lane] = row[r];
    }

    grid.sync();

    // ---- phase 2: mirror lower triangle ----
    for (int p = bid * NWV_ + wv; p < B_ * TPI_; p += GRID_ * NWV_) {
        const int b  = p / TPI_;
        const int p2 = p % TPI_;
        int wi = (int)((1.0f + sqrtf((float)(8 * p2 + 1))) * 0.5f);
        while (wi * (wi - 1) / 2 > p2) --wi;
        while ((wi + 1) * wi / 2 <= p2) ++wi;
        const int wj = p2 - wi * (wi - 1) / 2;   // wj < wi
        const size_t bN = (size_t)b * N_;

        u64 x = adj[(bN + wj * 64 + lane) * (size_t)NW_ + wi];

        const u64 M[6] = {0x00000000FFFFFFFFull, 0x0000FFFF0000FFFFull,
                          0x00FF00FF00FF00FFull, 0x0F0F0F0F0F0F0F0Full,
                          0x3333333333333333ull, 0x5555555555555555ull};
#pragma unroll
        for (int si = 0; si < 6; ++si) {
            const int s = 32 >> si;
            const u64 m = M[si];
            const u64 t = __shfl_xor(x, s);
            x = ((lane & s) == 0) ? ((x & m) | ((t & m) << s))
                                  : ((x & ~m) | ((t & ~m) >> s));
        }
        const int rowi = wi * 64 + lane;
        if (rowi < N_)
            adj[(bN + rowi) * (size_t)NW_ + wj] = x;
    }

    grid.sync();

    // ---- phase 3: acon + candidate emission (one wave per row) ----
    for (int g = bid * NWV_ + wv; g < B_ * N_; g += GRID_ * NWV_) {
        const int b = g / N_;
        const int i = g % N_;
        const size_t bN = (size_t)b * N_;

        u64 w = (lane < NW_) ? adj[(bN + i) * (size_t)NW_ + lane] : 0ull;

        float cm[C_];
#pragma unroll
        for (int k = 0; k < C_; ++k) cm[k] = 0.0f;

        while (w) {
            const int bit = __builtin_ctzll(w); w &= w - 1;
            const int j   = lane * 64 + bit;
            const float4* cp =
                reinterpret_cast<const float4*>(con + (bN + j) * C_);
            const float4 c0 = cp[0], c1 = cp[1], c2 = cp[2], c3 = cp[3];
            cm[0]  = fmaxf(cm[0],  c0.x); cm[1]  = fmaxf(cm[1],  c0.y);
            cm[2]  = fmaxf(cm[2],  c0.z); cm[3]  = fmaxf(cm[3],  c0.w);
            cm[4]  = fmaxf(cm[4],  c1.x); cm[5]  = fmaxf(cm[5],  c1.y);
            cm[6]  = fmaxf(cm[6],  c1.z); cm[7]  = fmaxf(cm[7],  c1.w);
            cm[8]  = fmaxf(cm[8],  c2.x); cm[9]  = fmaxf(cm[9],  c2.y);
            cm[10] = fmaxf(cm[10], c2.z); cm[11] = fmaxf(cm[11], c2.w);
            cm[12] = fmaxf(cm[12], c3.x); cm[13] = fmaxf(cm[13], c3.y);
            cm[14] = fmaxf(cm[14], c3.z); cm[15] = fmaxf(cm[15], c3.w);
        }

#pragma unroll
        for (int off = 1; off < 64; off <<= 1) {
#pragma unroll
            for (int k = 0; k < C_; ++k)
                cm[k] = fmaxf(cm[k], __shfl_xor(cm[k], off));
        }
        if (lane == 0) {
            const float4* cp =
                reinterpret_cast<const float4*>(con + (bN + i) * C_);
            const float4 c0 = cp[0], c1 = cp[1], c2 = cp[2], c3 = cp[3];
            const float4* pp =
                reinterpret_cast<const float4*>(pro + (bN + i) * C_);
            const float4 p0 = pp[0], p1 = pp[1], p2 = pp[2], p3 = pp[3];
            const float4* fp = reinterpret_cast<const float4*>(conf);
            const float4 f0 = fp[0], f1 = fp[1], f2 = fp[2], f3 = fp[3];
            const float th[C_] = {
                fmaxf(cm[0],  c0.x), fmaxf(cm[1],  c0.y),
                fmaxf(cm[2],  c0.z), fmaxf(cm[3],  c0.w),
                fmaxf(cm[4],  c1.x), fmaxf(cm[5],  c1.y),
                fmaxf(cm[6],  c1.z), fmaxf(cm[7],  c1.w),
                fmaxf(cm[8],  c2.x), fmaxf(cm[9],  c2.y),
                fmaxf(cm[10], c2.z), fmaxf(cm[11], c2.w),
                fmaxf(cm[12], c3.x), fmaxf(cm[13], c3.y),
                fmaxf(cm[14], c3.z), fmaxf(cm[15], c3.w)};
            const float pr[C_] = {p0.x, p0.y, p0.z, p0.w,
                                  p1.x, p1.y, p1.z, p1.w,
                                  p2.x, p2.y, p2.z, p2.w,
                                  p3.x, p3.y, p3.z, p3.w};
            const float cf[C_] = {f0.x, f0.y, f0.z, f0.w,
                                  f1.x, f1.y, f1.z, f1.w,
                                  f2.x, f2.y, f2.z, f2.w,
                                  f3.x, f3.y, f3.z, f3.w};
#pragma unroll
            for (int k = 0; k < C_; ++k) {
                if (pr[k] >= cf[k] && pr[k] >= th[k]) {
                    const u32 pb = __float_as_uint(pr[k]);
                    const u32 pk = pb ^ ((pb >> 31) ? 0xFFFFFFFFu : 0x80000000u);
                    const u32 pos = atomicAdd(&cnt[(b * C_ + k) * 16], 1u);
                    cand[(size_t)(b * C_ + k) * N_ + pos] =
                        (((u64)(~pk)) << 32) | (u32)i;
                }
            }
        }
    }

    grid.sync();

    // ---- phase 4: sort + greedy + output (blocks 0..63) ----
    if (bid >= B_ * C_) return;
    const int bc = bid;
    const int b  = bc / C_;
    const size_t bN = (size_t)b * N_;

    const int T  = (int)cnt[bc * 16];
    const int TW = (T + 63) >> 6;                // candidate words
    for (int x = tid; x < TW * 64; x += NT_)     // coalesced + ~0 padding
        sm.nms.ov.keys[x] = (x < T) ? cand[(size_t)bc * N_ + x] : ~0ull;
    if (tid < NW_) sm.nms.vmask[tid] = 0ull;
    __syncthreads();

    // rank sort (asc; keys unique -> rank is a permutation)
    for (int xp = 0; xp * NT_ < T; ++xp) {
        const int x  = xp * NT_ + tid;
        const u64 kx = (x < T) ? sm.nms.ov.keys[x] : ~0ull;
        u32 rank = 0;
        for (int yb = 0; yb < TW; ++yb) {
            const u64 ky = sm.nms.ov.keys[yb * 64 + lane];   // coalesced
            const u32 kyl = (u32)ky, kyh = (u32)(ky >> 32);
#pragma unroll
            for (int l = 0; l < 64; ++l) {
                const u64 kb =
                    ((u64)(u32)__builtin_amdgcn_readlane((int)kyh, l) << 32)
                  |  (u64)(u32)__builtin_amdgcn_readlane((int)kyl, l);
                rank += (kb < kx) ? 1u : 0u;
            }
        }
        if (x < T) {
            const u32 i = (u32)(kx & 0xFFFFFFFFull);
            sm.nms.sidx[rank] = i;
            const u32 pk = ~((u32)(kx >> 32));
            const u32 pb = (pk & 0x80000000u) ? (pk ^ 0x80000000u) : ~pk;
            sm.nms.sscore[rank] = __uint_as_float(pb);
            atomicOr(&sm.nms.vmask[i >> 6], 1ull << (i & 63));
        }
    }
    __syncthreads();                     // keys dead; srows may overlay now

    // chunk-parallel greedy; stage chunk 0
#pragma unroll
    for (int rr = 0; rr < RPWG_; ++rr) {
        const int r = wv * RPWG_ + rr;
        const u32 idx = (r < T) ? sm.nms.sidx[r] : 0u;
        if (lane < NW_)
            sm.nms.ov.srows[0][r][lane] = adj[(bN + idx) * (size_t)NW_ + lane];
    }
    __syncthreads();

    u32 S = 0;                           // meaningful in wave 0
    const int NCH = (T + CH_ - 1) / CH_;
    for (int ch = 0; ch < NCH; ++ch) {
        const int cur = ch & 1, nxt = cur ^ 1;
        const int c0 = ch * CH_;
        const int cn = min(CH_, T - c0);
        const int havenext = (ch + 1 < NCH);

        // A: prefetch next chunk rows + intra-chunk masks (symmetry)
        u64 pre[RPWG_];
#pragma unroll
        for (int rr = 0; rr < RPWG_; ++rr) {
            const int r = wv * RPWG_ + rr;
            const int q = c0 + CH_ + r;
            const u32 idxn = (havenext && q < T) ? sm.nms.sidx[q] : 0u;
            pre[rr] = (havenext && lane < NW_)
                        ? adj[(bN + idxn) * (size_t)NW_ + lane] : 0ull;
        }
#pragma unroll
        for (int rr = 0; rr < RPWG_; ++rr) {
            const int r = wv * RPWG_ + rr;
            const u32 idxr = (c0 + r < T) ? sm.nms.sidx[c0 + r] : 0u;
            const u64 rj = sm.nms.ov.srows[cur][lane][idxr >> 6];
            const u64 ib = __ballot((lane < cn) && ((rj >> (idxr & 63)) & 1ull));
            if (lane == 0) sm.nms.sintra[r] = ib;
        }
        __syncthreads();

        // B: wave 0 parallel-peeling resolve + survivor emit
        if (wv == 0) {
            const u32 idxme = (c0 + lane < T) ? sm.nms.sidx[c0 + lane] : 0u;
            const u64 vm = sm.nms.vmask[idxme >> 6];
            u64 cv = __ballot((lane < cn) && ((vm >> (idxme & 63)) & 1ull));
            const u64 iv = sm.nms.sintra[lane];      // ALL in-chunk neighbors
            const u64 below = (1ull << lane) - 1ull;
            u64 accept = 0ull;
            while (cv) {
                const int ok = ((cv >> lane) & 1ull) &&
                               ((iv & below & cv) == 0ull);
                const u64 ar = __ballot(ok);
                u64 sup = ok ? iv : 0ull;
#pragma unroll
                for (int off = 1; off < 64; off <<= 1)
                    sup |= __shfl_xor(sup, off);
                accept |= ar;
                cv &= ~(ar | sup);
            }
            if (lane == 0) sm.nms.s_accept = accept;
            if ((accept >> lane) & 1ull) {
                const u32 pos = S + (u32)__popcll(accept & below);
                sm.nms.slist[pos]  = idxme;
                sm.nms.slistf[pos] = sm.nms.sscore[c0 + lane];
            }
            S += (u32)__popcll(accept);
        }
        __syncthreads();

        // C: parallel apply + store prefetched rows
        const u64 ac = sm.nms.s_accept;
        u64 acc = 0ull;
#pragma unroll
        for (int rr = 0; rr < RPWG_; ++rr) {
            const int r = wv * RPWG_ + rr;
            if ((ac >> r) & 1ull)                    // wave-uniform branch
                acc |= sm.nms.ov.srows[cur][r][min(lane, NW_ - 1)];
        }
        if (lane < NW_ && acc)
            atomicAnd(&sm.nms.vmask[lane], ~acc);
        if (havenext) {
#pragma unroll
            for (int rr = 0; rr < RPWG_; ++rr) {
                const int r = wv * RPWG_ + rr;
                if (lane < NW_) sm.nms.ov.srows[nxt][r][lane] = pre[rr];
            }
        }
        __syncthreads();
    }
    if (wv == 0 && lane == 0) sm.nms.s_S = S;
    __syncthreads();

    // output survivors only (rest pre-zeroed in phase 0)
    const int Sf = (int)sm.nms.s_S;
    const float s = scales[b];
    for (int r = tid; r < Sf; r += NT_) {
        const int idx = (int)sm.nms.slist[r];
        const float4 bx = reinterpret_cast<const float4*>(boxes)[bN + idx];
        const float scx = bx.x * s, scy = bx.y * s;
        const float sw  = bx.z * s, sh  = bx.w * s;
        float* o = out + ((size_t)bc * N_ + r) * 5;
        o[0] = scx - 0.5f * sw;
        o[1] = scy - 0.5f * sh;
        o[2] = scx + 0.5f * sw;
        o[3] = scy + 0.5f * sh;
        o[4] = sm.nms.slistf[r];
        out[(size_t)B_ * C_ * N_ * 5 + (size_t)bc * N_ + r] = 1.0f;
    }
}

// ---------------------------------------------------------------------------
extern "C" void kernel_launch(void* const* d_in, const int* in_sizes, int n_in,
                              void* d_out, int out_size, void* d_ws, size_t ws_size,
                              hipStream_t stream) {
    const float* pro    = (const float*)d_in[0];   // (B,N,C)
    const float* con    = (const float*)d_in[1];   // (B,N,C)
    const float* boxes  = (const float*)d_in[2];   // (B,N,4)
    const float* scales = (const float*)d_in[3];   // (B,)
    const float* conf   = (const float*)d_in[4];   // (C,)

    char* ws = (char*)d_ws;
    u64* adj = (u64*)ws;                                   // B*N*NW u64  (6.57 MB)
    size_t off = (size_t)B_ * N_ * NW_ * sizeof(u64);
    u64* cand = (u64*)(ws + off);                          // B*C*N u64   (1.84 MB)
    off += (size_t)B_ * C_ * N_ * sizeof(u64);
    u32* cnt = (u32*)(ws + off);                           // B*C*16 u32  (4 KB, padded)

    float* outp = (float*)d_out;
    int nout = out_size;
    void* args[] = {(void*)&pro, (void*)&con, (void*)&boxes, (void*)&scales,
                    (void*)&conf, (void*)&adj, (void*)&cand, (void*)&cnt,
                    (void*)&outp, (void*)&nout};
    hipLaunchCooperativeKernel((const void*)k_all, dim3(GRID_), dim3(NT_),
                               args, 0, stream);
}

// Round 7
// 197.839 us; speedup vs baseline: 1.4081x; 1.4081x over previous
//
#include <hip/hip_runtime.h>
#include <cstdint>

typedef unsigned long long u64;
typedef unsigned int u32;

#define B_ 4
#define N_ 3600
#define C_ 16
#define NW_ 57        // ceil(N/64) words of adjacency bitmask
#define NPAD_ 3648    // NW_*64
#define RPW_ 4        // rows per wave (k_adj)
#define RPB_ 16       // rows per block (k_adj, 4 waves)
#define TPI_ 1596     // transpose tiles per image: 57*56/2
#define HW0_ 1856     // j-half 0: words 0..28  (29 words)
#define HW1_ 1792     // j-half 1: words 29..56 (28 words)
#define CH_ 64        // greedy chunk size (candidates per resolution round)
#define NT_ 512       // threads in nms kernels
#define NWV_ 8        // waves in nms kernels
#define RPWG_ 8       // rows per wave in slow-path greedy (CH_/NWV_)
#define TMAX_ 512     // fast-path candidate cap (T~330 measured; 4-sigma < 400)
#define TWMX_ 8       // TMAX_/64
#define CPAD_ 9       // cmat row pad (odd word count -> 16-bank spread)

// ---------------------------------------------------------------------------
// K1: adjacency bitmask, UPPER-TRIANGLE only (words >= block's first word
// w0), LDS-staged j-range (proven R2/R4 structure). IoU exactly symmetric
// (fmin/fmax/add/mul commutative) -> bit(i,j)==bit(j,i); k_tr mirrors.
// Exact division-free IoU: round_f32(inter/denom) >= 0.4f  <=>
// inter > (0.4f - 2^-26)*denom in f64 (26x24-bit product exact; midpoint
// ties round-to-even below 0.4f -> false, matching strict '>'; denom==0 =>
// inter==0 => false = reference NaN>=0.4). Diagonal cleared post-hoc.
// ---------------------------------------------------------------------------
__global__ __launch_bounds__(256, 4) void k_adj(const float* __restrict__ boxes,
                                                u64* __restrict__ adj) {
#pragma clang fp contract(off)
    __shared__ float4 sbox[HW0_];
    const int tid  = threadIdx.x;
    const int lane = tid & 63;
    const int wv   = tid >> 6;
    const int g    = blockIdx.x;                 // 0 .. B*N/16-1
    const int b    = g / (N_ / RPB_);
    const int rg   = g % (N_ / RPB_);
    const int r0   = rg * RPB_ + wv * RPW_;
    const int w0   = rg >> 2;                    // first word (block-uniform)
    const size_t bN = (size_t)b * N_;

    float4 bi[RPW_];
    float  ai[RPW_];
#pragma unroll
    for (int r = 0; r < RPW_; ++r) {
        const float4 bx = reinterpret_cast<const float4*>(boxes)[bN + r0 + r];
        const float x1 = bx.x - bx.z * 0.5f;   // reference op order
        const float y1 = bx.y - bx.w * 0.5f;
        const float x2 = x1 + bx.z;
        const float y2 = y1 + bx.w;
        bi[r] = make_float4(x1, y1, x2, y2);
        ai[r] = (x2 - x1) * (y2 - y1);
    }
    const double MID = (double)0.4f - 0x1p-26;   // exact

    u64 row[RPW_];
#pragma unroll
    for (int r = 0; r < RPW_; ++r) row[r] = 0ull;

    int jbase = 0;
    for (int h = 0; h < 2; ++h) {
        const int cnt  = h ? HW1_ : HW0_;
        const int wlo  = jbase >> 6;
        const int wcnt = cnt >> 6;
        if (w0 < wlo + wcnt) {                   // block-uniform skip
            const int tw0 = max(w0 - wlo, 0);
            const int jj0 = tw0 << 6;
            __syncthreads();
            for (int jj = jj0 + tid; jj < cnt; jj += 256) {
                const int j = jbase + jj;
                float x1 = 0.f, y1 = 0.f, x2 = 0.f, y2 = 0.f;
                if (j < N_) {
                    const float4 bx = reinterpret_cast<const float4*>(boxes)[bN + j];
                    x1 = bx.x - bx.z * 0.5f;
                    y1 = bx.y - bx.w * 0.5f;
                    x2 = x1 + bx.z;
                    y2 = y1 + bx.w;
                }
                sbox[jj] = make_float4(x1, y1, x2, y2);
            }
            __syncthreads();

            for (int tw = tw0; tw < wcnt; ++tw) {
                const int tglob = wlo + tw;
                const float4 bj = sbox[tw * 64 + lane];
                const float ajr = (bj.z - bj.x) * (bj.w - bj.y);
#pragma unroll
                for (int r = 0; r < RPW_; ++r) {
                    const float ltx = fmaxf(bi[r].x, bj.x);
                    const float lty = fmaxf(bi[r].y, bj.y);
                    const float rbx = fminf(bi[r].z, bj.z);
                    const float rby = fminf(bi[r].w, bj.w);
                    const float whx = fmaxf(rbx - ltx, 0.0f);
                    const float why = fmaxf(rby - lty, 0.0f);
                    const float inter = whx * why;
                    const float denom = (ai[r] + ajr) - inter;
                    const int pred = ((double)inter > MID * (double)denom);
                    const u64 m = __ballot(pred);
                    if (lane == tglob) row[r] = m;
                }
            }
        }
        jbase += cnt;
    }

#pragma unroll
    for (int r = 0; r < RPW_; ++r)
        if (lane == w0) row[r] &= ~(1ull << ((r0 + r) & 63));
#pragma unroll
    for (int r = 0; r < RPW_; ++r)
        if (lane >= w0 && lane < NW_)
            adj[(bN + r0 + r) * (size_t)NW_ + lane] = row[r];
}

// ---------------------------------------------------------------------------
// K1t: mirror the lower triangle (6-step shfl_xor block-swap bit-transpose,
// one wave per 64x64 tile wi>wj). Block 0 also zeroes candidate counters.
// ---------------------------------------------------------------------------
__global__ __launch_bounds__(256) void k_tr(u64* __restrict__ adj,
                                            u32* __restrict__ cnt) {
    if (blockIdx.x == 0) {
        for (int x = threadIdx.x; x < B_ * C_ * 16; x += 256) cnt[x] = 0;
    }
    const int lane = threadIdx.x & 63;
    const int wv   = threadIdx.x >> 6;
    const int p    = blockIdx.x * 4 + wv;        // 0 .. B*TPI-1 (exact)
    const int b    = p / TPI_;
    const int p2   = p % TPI_;
    int wi = (int)((1.0f + sqrtf((float)(8 * p2 + 1))) * 0.5f);
    while (wi * (wi - 1) / 2 > p2) --wi;
    while ((wi + 1) * wi / 2 <= p2) ++wi;
    const int wj = p2 - wi * (wi - 1) / 2;       // wj < wi
    const size_t bN = (size_t)b * N_;

    u64 x = adj[(bN + wj * 64 + lane) * (size_t)NW_ + wi];

    const u64 M[6] = {0x00000000FFFFFFFFull, 0x0000FFFF0000FFFFull,
                      0x00FF00FF00FF00FFull, 0x0F0F0F0F0F0F0F0Full,
                      0x3333333333333333ull, 0x5555555555555555ull};
#pragma unroll
    for (int si = 0; si < 6; ++si) {
        const int s = 32 >> si;
        const u64 m = M[si];
        const u64 t = __shfl_xor(x, s);
        x = ((lane & s) == 0) ? ((x & m) | ((t & m) << s))
                              : ((x & ~m) | ((t & ~m) >> s));
    }
    const int rowi = wi * 64 + lane;
    if (rowi < N_)
        adj[(bN + rowi) * (size_t)NW_ + wj] = x;
}

// ---------------------------------------------------------------------------
// K1b: acon + candidate emission (proven R4/R5 code). One wave per row;
// sparse con gather + 6-step shuffle max-reduce; lane 0 evaluates
// valid0 = (p>=conf_c) && (p>=fmax(adj_con,con_c)) (exact: p>=a && p>=b <=>
// p>=fmax(a,b), non-NaN; adj_con init 0 matches where(adj,con,0), subsumes
// p>=0) and emits sort key (~pk)<<32|i via atomicAdd. Arrival order
// nondeterministic; keys unique -> sort deterministic.
// ---------------------------------------------------------------------------
__global__ __launch_bounds__(256) void k_acon(const u64* __restrict__ adj,
                                              const float* __restrict__ con,
                                              const float* __restrict__ pro,
                                              const float* __restrict__ conf,
                                              u64* __restrict__ cand,
                                              u32* __restrict__ cnt) {
    const int tid  = threadIdx.x;
    const int lane = tid & 63;
    const int wv   = tid >> 6;
    const int g    = blockIdx.x;                 // 0 .. B*N/4-1
    const int b    = g / (N_ / 4);
    const int i    = (g % (N_ / 4)) * 4 + wv;
    const size_t bN = (size_t)b * N_;

    u64 w = (lane < NW_) ? adj[(bN + i) * (size_t)NW_ + lane] : 0ull;

    float cm[C_];
#pragma unroll
    for (int k = 0; k < C_; ++k) cm[k] = 0.0f;

    while (w) {
        const int bit = __builtin_ctzll(w); w &= w - 1;
        const int j   = lane * 64 + bit;
        const float4* cp = reinterpret_cast<const float4*>(con + (bN + j) * C_);
        const float4 c0 = cp[0], c1 = cp[1], c2 = cp[2], c3 = cp[3];
        cm[0]  = fmaxf(cm[0],  c0.x); cm[1]  = fmaxf(cm[1],  c0.y);
        cm[2]  = fmaxf(cm[2],  c0.z); cm[3]  = fmaxf(cm[3],  c0.w);
        cm[4]  = fmaxf(cm[4],  c1.x); cm[5]  = fmaxf(cm[5],  c1.y);
        cm[6]  = fmaxf(cm[6],  c1.z); cm[7]  = fmaxf(cm[7],  c1.w);
        cm[8]  = fmaxf(cm[8],  c2.x); cm[9]  = fmaxf(cm[9],  c2.y);
        cm[10] = fmaxf(cm[10], c2.z); cm[11] = fmaxf(cm[11], c2.w);
        cm[12] = fmaxf(cm[12], c3.x); cm[13] = fmaxf(cm[13], c3.y);
        cm[14] = fmaxf(cm[14], c3.z); cm[15] = fmaxf(cm[15], c3.w);
    }

#pragma unroll
    for (int off = 1; off < 64; off <<= 1) {
#pragma unroll
        for (int k = 0; k < C_; ++k) cm[k] = fmaxf(cm[k], __shfl_xor(cm[k], off));
    }
    if (lane == 0) {
        const float4* cp = reinterpret_cast<const float4*>(con + (bN + i) * C_);
        const float4 c0 = cp[0], c1 = cp[1], c2 = cp[2], c3 = cp[3];
        const float4* pp = reinterpret_cast<const float4*>(pro + (bN + i) * C_);
        const float4 p0 = pp[0], p1 = pp[1], p2 = pp[2], p3 = pp[3];
        const float4* fp = reinterpret_cast<const float4*>(conf);
        const float4 f0 = fp[0], f1 = fp[1], f2 = fp[2], f3 = fp[3];
        const float th[C_] = {
            fmaxf(cm[0],  c0.x), fmaxf(cm[1],  c0.y),
            fmaxf(cm[2],  c0.z), fmaxf(cm[3],  c0.w),
            fmaxf(cm[4],  c1.x), fmaxf(cm[5],  c1.y),
            fmaxf(cm[6],  c1.z), fmaxf(cm[7],  c1.w),
            fmaxf(cm[8],  c2.x), fmaxf(cm[9],  c2.y),
            fmaxf(cm[10], c2.z), fmaxf(cm[11], c2.w),
            fmaxf(cm[12], c3.x), fmaxf(cm[13], c3.y),
            fmaxf(cm[14], c3.z), fmaxf(cm[15], c3.w)};
        const float pr[C_] = {p0.x, p0.y, p0.z, p0.w, p1.x, p1.y, p1.z, p1.w,
                              p2.x, p2.y, p2.z, p2.w, p3.x, p3.y, p3.z, p3.w};
        const float cf[C_] = {f0.x, f0.y, f0.z, f0.w, f1.x, f1.y, f1.z, f1.w,
                              f2.x, f2.y, f2.z, f2.w, f3.x, f3.y, f3.z, f3.w};
#pragma unroll
        for (int k = 0; k < C_; ++k) {
            if (pr[k] >= cf[k] && pr[k] >= th[k]) {
                const u32 pb = __float_as_uint(pr[k]);
                const u32 pk = pb ^ ((pb >> 31) ? 0xFFFFFFFFu : 0x80000000u);
                const u32 pos = atomicAdd(&cnt[(b * C_ + k) * 16], 1u);
                cand[(size_t)(b * C_ + k) * N_ + pos] =
                    (((u64)(~pk)) << 32) | (u32)i;
            }
        }
    }
}

// ---------------------------------------------------------------------------
// K2 FAST PATH (T <= TMAX_): candidate-space NMS, one 512-thread block per
// (b,c). The entire greedy runs on a T x T bit-matrix in LDS — no global
// row staging, no prefetch, no 57-word masks, 2 barriers/chunk.
//  1) load keys (coalesced), readlane rank sort -> sidx/sscore.
//  2) build cmat: per candidate row r, ONE coalesced 456-B adj row load
//     (word lane), then per 64-candidate group: sidx gather + variable-lane
//     shfl + ballot. cmat[r][g] bit l = adjacency(cand r, cand g*64+l).
//     Padding columns (>=T) produce garbage bits but are masked everywhere.
//  3) greedy: valid[] = all-ones in candidate space (all candidates are
//     valid0 by construction). Per chunk: wave 0 reads iv=cmat[c0+lane][ch]
//     directly (intra = same word) and peels (proven R6 logic: round-accept
//     candidates with no earlier UNDECIDED neighbor == sequential greedy);
//     then waves apply suppression to later words g>ch in parallel.
//  4) full-slice output incl. zeros (absorbs memset).
// Exactness: same accept semantics as the proven chunked greedy; survivor
// order == greedy order == reference order.
// ---------------------------------------------------------------------------
__global__ __launch_bounds__(NT_) void k_nms_fast(const u64* __restrict__ cand,
                                                  const u32* __restrict__ cnt,
                                                  const u64* __restrict__ adj,
                                                  const float* __restrict__ boxes,
                                                  const float* __restrict__ scales,
                                                  float* __restrict__ out) {
#pragma clang fp contract(off)
    __shared__ union {
        u64 keys[TMAX_];                 // 4 KB   (live: sort)
        u64 cmat[TMAX_][CPAD_];          // 36.9 KB (live: build/greedy)
    } ov;
    __shared__ u32 sidx[TMAX_];
    __shared__ float sscore[TMAX_];
    __shared__ u32 slist[TMAX_];
    __shared__ float slistf[TMAX_];
    __shared__ u64 valid[TWMX_];
    __shared__ u64 s_accept;
    __shared__ u32 s_S;
    const int tid  = threadIdx.x;
    const int lane = tid & 63;
    const int wv   = tid >> 6;
    const int bc   = blockIdx.x;
    const int b    = bc / C_;
    const size_t bN = (size_t)b * N_;

    const int T = (int)cnt[bc * 16];
    if (T > TMAX_) return;                       // slow path handles
    const int TW = (T + 63) >> 6;

    for (int x = tid; x < TW * 64; x += NT_)
        ov.keys[x] = (x < T) ? cand[(size_t)bc * N_ + x] : ~0ull;
    if (tid < TWMX_) valid[tid] = ~0ull;
    __syncthreads();

    // --- sort: readlane rank (keys unique -> rank is a permutation) ---
    {
        const u64 kx = (tid < T) ? ov.keys[tid] : ~0ull;
        u32 rank = 0;
        for (int yb = 0; yb < TW; ++yb) {
            const u64 ky = ov.keys[yb * 64 + lane];      // coalesced
            const u32 kyl = (u32)ky, kyh = (u32)(ky >> 32);
#pragma unroll
            for (int l = 0; l < 64; ++l) {
                const u64 kb =
                    ((u64)(u32)__builtin_amdgcn_readlane((int)kyh, l) << 32)
                  |  (u64)(u32)__builtin_amdgcn_readlane((int)kyl, l);
                rank += (kb < kx) ? 1u : 0u;
            }
        }
        if (tid < T) {
            sidx[rank] = (u32)(kx & 0xFFFFFFFFull);
            const u32 pk = ~((u32)(kx >> 32));
            const u32 pb = (pk & 0x80000000u) ? (pk ^ 0x80000000u) : ~pk;
            sscore[rank] = __uint_as_float(pb);
        }
        for (int x = T + tid; x < TW * 64; x += NT_) sidx[x] = 0u;  // pad
    }
    __syncthreads();                     // keys dead; cmat may overlay now

    // --- build candidate-space adjacency matrix ---
    for (int r = wv; r < T; r += NWV_) {
        const u32 ir = sidx[r];
        const u64 w = (lane < NW_) ? adj[(bN + ir) * (size_t)NW_ + lane] : 0ull;
        for (int g = 0; g < TW; ++g) {
            const u32 jc = sidx[g * 64 + lane];
            const u64 wj = __shfl(w, (int)(jc >> 6));
            const u64 bm = __ballot((wj >> (jc & 63)) & 1ull);
            if (lane == 0) ov.cmat[r][g] = bm;
        }
    }
    __syncthreads();

    // --- chunked greedy in candidate space ---
    u32 S = 0;                           // meaningful in wave 0
    const int NCH = (T + CH_ - 1) / CH_;
    for (int ch = 0; ch < NCH; ++ch) {
        const int c0 = ch * CH_;
        const int cn = min(CH_, T - c0);

        // wave 0: peel (parallel peeling == sequential greedy, R6-proven)
        if (wv == 0) {
            const u64 cmask = (cn >= 64) ? ~0ull : ((1ull << cn) - 1ull);
            u64 cv = valid[ch] & cmask;
            const u64 iv = (lane < cn) ? ov.cmat[c0 + lane][ch] : 0ull;
            const u64 below = (1ull << lane) - 1ull;
            u64 accept = 0ull;
            while (cv) {
                const int ok = ((cv >> lane) & 1ull) &&
                               ((iv & below & cv) == 0ull);
                const u64 ar = __ballot(ok);
                u64 sup = ok ? iv : 0ull;
#pragma unroll
                for (int off = 1; off < 64; off <<= 1)
                    sup |= __shfl_xor(sup, off);
                accept |= ar;
                cv &= ~(ar | sup);
            }
            if (lane == 0) s_accept = accept;
            if ((accept >> lane) & 1ull) {
                const u32 pos = S + (u32)__popcll(accept & below);
                slist[pos]  = sidx[c0 + lane];
                slistf[pos] = sscore[c0 + lane];
            }
            S += (u32)__popcll(accept);
        }
        __syncthreads();

        // all waves: suppress later words in parallel (one wave per word)
        const u64 ac = s_accept;
        const int g = ch + 1 + wv;
        if (g < TW && ac) {
            u64 sup = ((ac >> lane) & 1ull) ? ov.cmat[c0 + lane][g] : 0ull;
#pragma unroll
            for (int off = 1; off < 64; off <<= 1)
                sup |= __shfl_xor(sup, off);
            if (lane == 0) valid[g] &= ~sup;
        }
        __syncthreads();
    }
    if (wv == 0 && lane == 0) s_S = S;
    __syncthreads();

    // --- full-slice output (zeros past Sf; absorbs memset) ---
    const int Sf = (int)s_S;
    const float s = scales[b];
    for (int r = tid; r < N_; r += NT_) {
        float o0 = 0.f, o1 = 0.f, o2 = 0.f, o3 = 0.f, o4 = 0.f, mk = 0.f;
        if (r < Sf) {
            const int idx = (int)slist[r];
            const float4 bx = reinterpret_cast<const float4*>(boxes)[bN + idx];
            const float scx = bx.x * s, scy = bx.y * s;
            const float sw  = bx.z * s, sh  = bx.w * s;
            o0 = scx - 0.5f * sw;
            o1 = scy - 0.5f * sh;
            o2 = scx + 0.5f * sw;
            o3 = scy + 0.5f * sh;
            o4 = slistf[r];
            mk = 1.0f;
        }
        float* o = out + ((size_t)bc * N_ + r) * 5;
        o[0] = o0; o[1] = o1; o[2] = o2; o[3] = o3; o[4] = o4;
        out[(size_t)B_ * C_ * N_ * 5 + (size_t)bc * N_ + r] = mk;
    }
}

// ---------------------------------------------------------------------------
// K2 SLOW PATH (T > TMAX_ only; correctness insurance, trivially exits on
// this data): verbatim proven R5 kernel (N-space chunked greedy).
// ---------------------------------------------------------------------------
union OvT {
    u64 keys[NPAD_];
    u64 srows[2][CH_][NW_];
};

__global__ __launch_bounds__(NT_) void k_nms_slow(const u64* __restrict__ cand,
                                                  const u32* __restrict__ cnt,
                                                  const u64* __restrict__ adj,
                                                  const float* __restrict__ boxes,
                                                  const float* __restrict__ scales,
                                                  float* __restrict__ out) {
#pragma clang fp contract(off)
    __shared__ OvT ov;
    __shared__ u32 sidx[NPAD_];
    __shared__ float sscore[NPAD_];
    __shared__ u64 sintra[CH_];
    __shared__ u64 vmask[NW_];
    __shared__ u64 s_accept;
    __shared__ u32 slist[NPAD_];
    __shared__ float slistf[NPAD_];
    __shared__ u32 s_S;
    const int tid  = threadIdx.x;
    const int lane = tid & 63;
    const int wv   = tid >> 6;
    const int bc   = blockIdx.x;
    const int b    = bc / C_;
    const size_t bN = (size_t)b * N_;

    const int T  = (int)cnt[bc * 16];
    if (T <= TMAX_) return;                      // fast path handled
    const int TW = (T + 63) >> 6;
    for (int x = tid; x < TW * 64; x += NT_)
        ov.keys[x] = (x < T) ? cand[(size_t)bc * N_ + x] : ~0ull;
    if (tid < NW_) vmask[tid] = 0ull;
    __syncthreads();

    for (int xp = 0; xp * NT_ < T; ++xp) {
        const int x  = xp * NT_ + tid;
        const u64 kx = (x < T) ? ov.keys[x] : ~0ull;
        u32 rank = 0;
        for (int yb = 0; yb < TW; ++yb) {
            const u64 ky = ov.keys[yb * 64 + lane];
            const u32 kyl = (u32)ky, kyh = (u32)(ky >> 32);
#pragma unroll
            for (int l = 0; l < 64; ++l) {
                const u64 kb =
                    ((u64)(u32)__builtin_amdgcn_readlane((int)kyh, l) << 32)
                  |  (u64)(u32)__builtin_amdgcn_readlane((int)kyl, l);
                rank += (kb < kx) ? 1u : 0u;
            }
        }
        if (x < T) {
            const u32 i = (u32)(kx & 0xFFFFFFFFull);
            sidx[rank] = i;
            const u32 pk = ~((u32)(kx >> 32));
            const u32 pb = (pk & 0x80000000u) ? (pk ^ 0x80000000u) : ~pk;
            sscore[rank] = __uint_as_float(pb);
            atomicOr(&vmask[i >> 6], 1ull << (i & 63));
        }
    }
    __syncthreads();

#pragma unroll
    for (int rr = 0; rr < RPWG_; ++rr) {
        const int r = wv * RPWG_ + rr;
        const u32 idx = (r < T) ? sidx[r] : 0u;
        if (lane < NW_)
            ov.srows[0][r][lane] = adj[(bN + idx) * (size_t)NW_ + lane];
    }
    __syncthreads();

    u32 S = 0;
    const int NCH = (T + CH_ - 1) / CH_;
    for (int ch = 0; ch < NCH; ++ch) {
        const int cur = ch & 1, nxt = cur ^ 1;
        const int c0 = ch * CH_;
        const int cn = min(CH_, T - c0);
        const int havenext = (ch + 1 < NCH);

        u64 pre[RPWG_];
#pragma unroll
        for (int rr = 0; rr < RPWG_; ++rr) {
            const int r = wv * RPWG_ + rr;
            const int q = c0 + CH_ + r;
            const u32 idxn = (havenext && q < T) ? sidx[q] : 0u;
            pre[rr] = (havenext && lane < NW_)
                        ? adj[(bN + idxn) * (size_t)NW_ + lane] : 0ull;
        }
#pragma unroll
        for (int rr = 0; rr < RPWG_; ++rr) {
            const int r = wv * RPWG_ + rr;
            const u32 idxr = (c0 + r < T) ? sidx[c0 + r] : 0u;
            const u64 rj = ov.srows[cur][lane][idxr >> 6];
            const u64 ib = __ballot((lane < cn) && ((rj >> (idxr & 63)) & 1ull));
            if (lane == 0) sintra[r] = ib;
        }
        __syncthreads();

        if (wv == 0) {
            const u32 idxme = (c0 + lane < T) ? sidx[c0 + lane] : 0u;
            const u64 vm = vmask[idxme >> 6];
            u64 cv = __ballot((lane < cn) && ((vm >> (idxme & 63)) & 1ull));
            const u64 iv = sintra[lane];
            const u64 below = (1ull << lane) - 1ull;
            u64 accept = 0ull;
            while (cv) {
                const int ok = ((cv >> lane) & 1ull) &&
                               ((iv & below & cv) == 0ull);
                const u64 ar = __ballot(ok);
                u64 sup = ok ? iv : 0ull;
#pragma unroll
                for (int off = 1; off < 64; off <<= 1)
                    sup |= __shfl_xor(sup, off);
                accept |= ar;
                cv &= ~(ar | sup);
            }
            if (lane == 0) s_accept = accept;
            if ((accept >> lane) & 1ull) {
                const u32 pos = S + (u32)__popcll(accept & below);
                slist[pos]  = idxme;
                slistf[pos] = sscore[c0 + lane];
            }
            S += (u32)__popcll(accept);
        }
        __syncthreads();

        const u64 ac = s_accept;
        u64 acc = 0ull;
#pragma unroll
        for (int rr = 0; rr < RPWG_; ++rr) {
            const int r = wv * RPWG_ + rr;
            if ((ac >> r) & 1ull)
                acc |= ov.srows[cur][r][min(lane, NW_ - 1)];
        }
        if (lane < NW_ && acc)
            atomicAnd(&vmask[lane], ~acc);
        if (havenext) {
#pragma unroll
            for (int rr = 0; rr < RPWG_; ++rr) {
                const int r = wv * RPWG_ + rr;
                if (lane < NW_) ov.srows[nxt][r][lane] = pre[rr];
            }
        }
        __syncthreads();
    }
    if (wv == 0 && lane == 0) s_S = S;
    __syncthreads();

    const int Sf = (int)s_S;
    const float s = scales[b];
    for (int r = tid; r < N_; r += NT_) {
        float o0 = 0.f, o1 = 0.f, o2 = 0.f, o3 = 0.f, o4 = 0.f, mk = 0.f;
        if (r < Sf) {
            const int idx = (int)slist[r];
            const float4 bx = reinterpret_cast<const float4*>(boxes)[bN + idx];
            const float scx = bx.x * s, scy = bx.y * s;
            const float sw  = bx.z * s, sh  = bx.w * s;
            o0 = scx - 0.5f * sw;
            o1 = scy - 0.5f * sh;
            o2 = scx + 0.5f * sw;
            o3 = scy + 0.5f * sh;
            o4 = slistf[r];
            mk = 1.0f;
        }
        float* o = out + ((size_t)bc * N_ + r) * 5;
        o[0] = o0; o[1] = o1; o[2] = o2; o[3] = o3; o[4] = o4;
        out[(size_t)B_ * C_ * N_ * 5 + (size_t)bc * N_ + r] = mk;
    }
}

// ---------------------------------------------------------------------------
extern "C" void kernel_launch(void* const* d_in, const int* in_sizes, int n_in,
                              void* d_out, int out_size, void* d_ws, size_t ws_size,
                              hipStream_t stream) {
    const float* pro    = (const float*)d_in[0];   // (B,N,C)
    const float* con    = (const float*)d_in[1];   // (B,N,C)
    const float* boxes  = (const float*)d_in[2];   // (B,N,4)
    const float* scales = (const float*)d_in[3];   // (B,)
    const float* conf   = (const float*)d_in[4];   // (C,)

    char* ws = (char*)d_ws;
    u64* adj = (u64*)ws;                                   // B*N*NW u64  (6.57 MB)
    size_t off = (size_t)B_ * N_ * NW_ * sizeof(u64);
    u64* cand = (u64*)(ws + off);                          // B*C*N u64   (1.84 MB)
    off += (size_t)B_ * C_ * N_ * sizeof(u64);
    u32* cnt = (u32*)(ws + off);                           // B*C*16 u32  (padded)

    k_adj     <<<B_ * N_ / RPB_, 256, 0, stream>>>(boxes, adj);
    k_tr      <<<B_ * TPI_ / 4,  256, 0, stream>>>(adj, cnt);
    k_acon    <<<B_ * N_ / 4,    256, 0, stream>>>(adj, con, pro, conf, cand, cnt);
    k_nms_fast<<<B_ * C_,        NT_, 0, stream>>>(cand, cnt, adj, boxes,
                                                   scales, (float*)d_out);
    k_nms_slow<<<B_ * C_,        NT_, 0, stream>>>(cand, cnt, adj, boxes,
                                                   scales, (float*)d_out);
}

// Round 8
// 195.780 us; speedup vs baseline: 1.4229x; 1.0105x over previous
//
#include <hip/hip_runtime.h>
#include <cstdint>

typedef unsigned long long u64;
typedef unsigned int u32;

#define B_ 4
#define N_ 3600
#define C_ 16
#define NW_ 57        // ceil(N/64) words of adjacency bitmask
#define NPAD_ 3648    // NW_*64
#define RPW_ 4        // rows per wave (k_adj)
#define RPB_ 16       // rows per block (k_adj, 4 waves)
#define TPI_ 1596     // transpose tiles per image: 57*56/2
#define HW0_ 1856     // j-half 0: words 0..28  (29 words)
#define HW1_ 1792     // j-half 1: words 29..56 (28 words)
#define CH_ 64        // greedy chunk size (candidates per resolution round)
#define NT_ 512       // threads in nms kernels
#define NWV_ 8        // waves in nms kernels
#define RPWG_ 8       // rows per wave in slow-path greedy (CH_/NWV_)
#define TMAX_ 512     // fast-path candidate cap (T~330 measured)
#define TWMX_ 8       // TMAX_/64
#define CPAD_ 9       // cmat row pad (odd word count -> bank spread)

// ---------------------------------------------------------------------------
// K1: adjacency bitmask, UPPER-TRIANGLE only (words >= block's first word
// w0), LDS-staged j-range (proven R2/R4 structure). IoU exactly symmetric
// (fmin/fmax/add/mul commutative) -> bit(i,j)==bit(j,i); k_tr mirrors.
// Exact division-free IoU: round_f32(inter/denom) >= 0.4f  <=>
// inter > (0.4f - 2^-26)*denom in f64 (26x24-bit product exact; midpoint
// ties round-to-even below 0.4f -> false, matching strict '>'; denom==0 =>
// inter==0 => false = reference NaN>=0.4). Diagonal cleared post-hoc.
// ---------------------------------------------------------------------------
__global__ __launch_bounds__(256, 4) void k_adj(const float* __restrict__ boxes,
                                                u64* __restrict__ adj) {
#pragma clang fp contract(off)
    __shared__ float4 sbox[HW0_];
    const int tid  = threadIdx.x;
    const int lane = tid & 63;
    const int wv   = tid >> 6;
    const int g    = blockIdx.x;                 // 0 .. B*N/16-1
    const int b    = g / (N_ / RPB_);
    const int rg   = g % (N_ / RPB_);
    const int r0   = rg * RPB_ + wv * RPW_;
    const int w0   = rg >> 2;                    // first word (block-uniform)
    const size_t bN = (size_t)b * N_;

    float4 bi[RPW_];
    float  ai[RPW_];
#pragma unroll
    for (int r = 0; r < RPW_; ++r) {
        const float4 bx = reinterpret_cast<const float4*>(boxes)[bN + r0 + r];
        const float x1 = bx.x - bx.z * 0.5f;   // reference op order
        const float y1 = bx.y - bx.w * 0.5f;
        const float x2 = x1 + bx.z;
        const float y2 = y1 + bx.w;
        bi[r] = make_float4(x1, y1, x2, y2);
        ai[r] = (x2 - x1) * (y2 - y1);
    }
    const double MID = (double)0.4f - 0x1p-26;   // exact

    u64 row[RPW_];
#pragma unroll
    for (int r = 0; r < RPW_; ++r) row[r] = 0ull;

    int jbase = 0;
    for (int h = 0; h < 2; ++h) {
        const int cnt  = h ? HW1_ : HW0_;
        const int wlo  = jbase >> 6;
        const int wcnt = cnt >> 6;
        if (w0 < wlo + wcnt) {                   // block-uniform skip
            const int tw0 = max(w0 - wlo, 0);
            const int jj0 = tw0 << 6;
            __syncthreads();
            for (int jj = jj0 + tid; jj < cnt; jj += 256) {
                const int j = jbase + jj;
                float x1 = 0.f, y1 = 0.f, x2 = 0.f, y2 = 0.f;
                if (j < N_) {
                    const float4 bx = reinterpret_cast<const float4*>(boxes)[bN + j];
                    x1 = bx.x - bx.z * 0.5f;
                    y1 = bx.y - bx.w * 0.5f;
                    x2 = x1 + bx.z;
                    y2 = y1 + bx.w;
                }
                sbox[jj] = make_float4(x1, y1, x2, y2);
            }
            __syncthreads();

            for (int tw = tw0; tw < wcnt; ++tw) {
                const int tglob = wlo + tw;
                const float4 bj = sbox[tw * 64 + lane];
                const float ajr = (bj.z - bj.x) * (bj.w - bj.y);
#pragma unroll
                for (int r = 0; r < RPW_; ++r) {
                    const float ltx = fmaxf(bi[r].x, bj.x);
                    const float lty = fmaxf(bi[r].y, bj.y);
                    const float rbx = fminf(bi[r].z, bj.z);
                    const float rby = fminf(bi[r].w, bj.w);
                    const float whx = fmaxf(rbx - ltx, 0.0f);
                    const float why = fmaxf(rby - lty, 0.0f);
                    const float inter = whx * why;
                    const float denom = (ai[r] + ajr) - inter;
                    const int pred = ((double)inter > MID * (double)denom);
                    const u64 m = __ballot(pred);
                    if (lane == tglob) row[r] = m;
                }
            }
        }
        jbase += cnt;
    }

#pragma unroll
    for (int r = 0; r < RPW_; ++r)
        if (lane == w0) row[r] &= ~(1ull << ((r0 + r) & 63));
#pragma unroll
    for (int r = 0; r < RPW_; ++r)
        if (lane >= w0 && lane < NW_)
            adj[(bN + r0 + r) * (size_t)NW_ + lane] = row[r];
}

// ---------------------------------------------------------------------------
// K1t: mirror the lower triangle (6-step shfl_xor block-swap bit-transpose,
// one wave per 64x64 tile wi>wj). Block 0 also zeroes candidate counters.
// ---------------------------------------------------------------------------
__global__ __launch_bounds__(256) void k_tr(u64* __restrict__ adj,
                                            u32* __restrict__ cnt) {
    if (blockIdx.x == 0) {
        for (int x = threadIdx.x; x < B_ * C_ * 16; x += 256) cnt[x] = 0;
    }
    const int lane = threadIdx.x & 63;
    const int wv   = threadIdx.x >> 6;
    const int p    = blockIdx.x * 4 + wv;        // 0 .. B*TPI-1 (exact)
    const int b    = p / TPI_;
    const int p2   = p % TPI_;
    int wi = (int)((1.0f + sqrtf((float)(8 * p2 + 1))) * 0.5f);
    while (wi * (wi - 1) / 2 > p2) --wi;
    while ((wi + 1) * wi / 2 <= p2) ++wi;
    const int wj = p2 - wi * (wi - 1) / 2;       // wj < wi
    const size_t bN = (size_t)b * N_;

    u64 x = adj[(bN + wj * 64 + lane) * (size_t)NW_ + wi];

    const u64 M[6] = {0x00000000FFFFFFFFull, 0x0000FFFF0000FFFFull,
                      0x00FF00FF00FF00FFull, 0x0F0F0F0F0F0F0F0Full,
                      0x3333333333333333ull, 0x5555555555555555ull};
#pragma unroll
    for (int si = 0; si < 6; ++si) {
        const int s = 32 >> si;
        const u64 m = M[si];
        const u64 t = __shfl_xor(x, s);
        x = ((lane & s) == 0) ? ((x & m) | ((t & m) << s))
                              : ((x & ~m) | ((t & ~m) >> s));
    }
    const int rowi = wi * 64 + lane;
    if (rowi < N_)
        adj[(bN + rowi) * (size_t)NW_ + wj] = x;
}

// ---------------------------------------------------------------------------
// K1b: acon + candidate emission (proven R4/R5 code). One wave per row;
// sparse con gather + 6-step shuffle max-reduce; lane 0 evaluates
// valid0 = (p>=conf_c) && (p>=fmax(adj_con,con_c)) (exact: p>=a && p>=b <=>
// p>=fmax(a,b), non-NaN; adj_con init 0 matches where(adj,con,0), subsumes
// p>=0) and emits sort key (~pk)<<32|i via atomicAdd. Arrival order
// nondeterministic; keys unique -> sort deterministic.
// ---------------------------------------------------------------------------
__global__ __launch_bounds__(256) void k_acon(const u64* __restrict__ adj,
                                              const float* __restrict__ con,
                                              const float* __restrict__ pro,
                                              const float* __restrict__ conf,
                                              u64* __restrict__ cand,
                                              u32* __restrict__ cnt) {
    const int tid  = threadIdx.x;
    const int lane = tid & 63;
    const int wv   = tid >> 6;
    const int g    = blockIdx.x;                 // 0 .. B*N/4-1
    const int b    = g / (N_ / 4);
    const int i    = (g % (N_ / 4)) * 4 + wv;
    const size_t bN = (size_t)b * N_;

    u64 w = (lane < NW_) ? adj[(bN + i) * (size_t)NW_ + lane] : 0ull;

    float cm[C_];
#pragma unroll
    for (int k = 0; k < C_; ++k) cm[k] = 0.0f;

    while (w) {
        const int bit = __builtin_ctzll(w); w &= w - 1;
        const int j   = lane * 64 + bit;
        const float4* cp = reinterpret_cast<const float4*>(con + (bN + j) * C_);
        const float4 c0 = cp[0], c1 = cp[1], c2 = cp[2], c3 = cp[3];
        cm[0]  = fmaxf(cm[0],  c0.x); cm[1]  = fmaxf(cm[1],  c0.y);
        cm[2]  = fmaxf(cm[2],  c0.z); cm[3]  = fmaxf(cm[3],  c0.w);
        cm[4]  = fmaxf(cm[4],  c1.x); cm[5]  = fmaxf(cm[5],  c1.y);
        cm[6]  = fmaxf(cm[6],  c1.z); cm[7]  = fmaxf(cm[7],  c1.w);
        cm[8]  = fmaxf(cm[8],  c2.x); cm[9]  = fmaxf(cm[9],  c2.y);
        cm[10] = fmaxf(cm[10], c2.z); cm[11] = fmaxf(cm[11], c2.w);
        cm[12] = fmaxf(cm[12], c3.x); cm[13] = fmaxf(cm[13], c3.y);
        cm[14] = fmaxf(cm[14], c3.z); cm[15] = fmaxf(cm[15], c3.w);
    }

#pragma unroll
    for (int off = 1; off < 64; off <<= 1) {
#pragma unroll
        for (int k = 0; k < C_; ++k) cm[k] = fmaxf(cm[k], __shfl_xor(cm[k], off));
    }
    if (lane == 0) {
        const float4* cp = reinterpret_cast<const float4*>(con + (bN + i) * C_);
        const float4 c0 = cp[0], c1 = cp[1], c2 = cp[2], c3 = cp[3];
        const float4* pp = reinterpret_cast<const float4*>(pro + (bN + i) * C_);
        const float4 p0 = pp[0], p1 = pp[1], p2 = pp[2], p3 = pp[3];
        const float4* fp = reinterpret_cast<const float4*>(conf);
        const float4 f0 = fp[0], f1 = fp[1], f2 = fp[2], f3 = fp[3];
        const float th[C_] = {
            fmaxf(cm[0],  c0.x), fmaxf(cm[1],  c0.y),
            fmaxf(cm[2],  c0.z), fmaxf(cm[3],  c0.w),
            fmaxf(cm[4],  c1.x), fmaxf(cm[5],  c1.y),
            fmaxf(cm[6],  c1.z), fmaxf(cm[7],  c1.w),
            fmaxf(cm[8],  c2.x), fmaxf(cm[9],  c2.y),
            fmaxf(cm[10], c2.z), fmaxf(cm[11], c2.w),
            fmaxf(cm[12], c3.x), fmaxf(cm[13], c3.y),
            fmaxf(cm[14], c3.z), fmaxf(cm[15], c3.w)};
        const float pr[C_] = {p0.x, p0.y, p0.z, p0.w, p1.x, p1.y, p1.z, p1.w,
                              p2.x, p2.y, p2.z, p2.w, p3.x, p3.y, p3.z, p3.w};
        const float cf[C_] = {f0.x, f0.y, f0.z, f0.w, f1.x, f1.y, f1.z, f1.w,
                              f2.x, f2.y, f2.z, f2.w, f3.x, f3.y, f3.z, f3.w};
#pragma unroll
        for (int k = 0; k < C_; ++k) {
            if (pr[k] >= cf[k] && pr[k] >= th[k]) {
                const u32 pb = __float_as_uint(pr[k]);
                const u32 pk = pb ^ ((pb >> 31) ? 0xFFFFFFFFu : 0x80000000u);
                const u32 pos = atomicAdd(&cnt[(b * C_ + k) * 16], 1u);
                cand[(size_t)(b * C_ + k) * N_ + pos] =
                    (((u64)(~pk)) << 32) | (u32)i;
            }
        }
    }
}

// ---------------------------------------------------------------------------
// K2 FAST PATH (T <= TMAX_): candidate-space NMS, one 512-thread block per
// (b,c). cmat is built by DIRECT IoU RECOMPUTATION among the T candidates
// (T*TW*64 ~ 127K lane-tests/block, 15x less arithmetic than k_adj and no
// adj reads at all) — pure VALU + ballot, candidate boxes staged stride-1
// in LDS. R7's shfl(w, data-dependent-lane) build compiled to ds_bpermute
// pairs (481K bank conflicts, +27 us); this has zero permutes.
// Bit-exactness: identical FP ops in identical order as k_adj -> identical
// bits; self-pair excluded by candidate-position compare (== diagonal).
// Greedy: R6/R7-proven parallel peeling == sequential greedy; 2 barriers
// per chunk; cross-chunk suppression on TW words. Full-slice output incl.
// zeros (absorbs memset).
// ---------------------------------------------------------------------------
__global__ __launch_bounds__(NT_) void k_nms_fast(const u64* __restrict__ cand,
                                                  const u32* __restrict__ cnt,
                                                  const float* __restrict__ boxes,
                                                  const float* __restrict__ scales,
                                                  float* __restrict__ out) {
#pragma clang fp contract(off)
    __shared__ union {
        u64 keys[TMAX_];                 // 4 KB   (live: sort)
        u64 cmat[TMAX_][CPAD_];          // 36.9 KB (live: build/greedy)
    } ov;
    __shared__ float4 cbox[TMAX_];       // candidate (x1,y1,x2,y2), 8 KB
    __shared__ u32 sidx[TMAX_];
    __shared__ float sscore[TMAX_];
    __shared__ u32 slist[TMAX_];
    __shared__ float slistf[TMAX_];
    __shared__ u64 valid[TWMX_];
    __shared__ u64 s_accept;
    __shared__ u32 s_S;
    const int tid  = threadIdx.x;
    const int lane = tid & 63;
    const int wv   = tid >> 6;
    const int bc   = blockIdx.x;
    const int b    = bc / C_;
    const size_t bN = (size_t)b * N_;
    const double MID = (double)0.4f - 0x1p-26;   // exact

    const int T = (int)cnt[bc * 16];
    if (T > TMAX_) return;                       // slow path handles
    const int TW = (T + 63) >> 6;

    for (int x = tid; x < TW * 64; x += NT_)
        ov.keys[x] = (x < T) ? cand[(size_t)bc * N_ + x] : ~0ull;
    if (tid < TWMX_) valid[tid] = ~0ull;
    __syncthreads();

    // --- sort: readlane rank (keys unique -> rank is a permutation) ---
    {
        const u64 kx = (tid < T) ? ov.keys[tid] : ~0ull;
        u32 rank = 0;
        for (int yb = 0; yb < TW; ++yb) {
            const u64 ky = ov.keys[yb * 64 + lane];      // coalesced
            const u32 kyl = (u32)ky, kyh = (u32)(ky >> 32);
#pragma unroll
            for (int l = 0; l < 64; ++l) {
                const u64 kb =
                    ((u64)(u32)__builtin_amdgcn_readlane((int)kyh, l) << 32)
                  |  (u64)(u32)__builtin_amdgcn_readlane((int)kyl, l);
                rank += (kb < kx) ? 1u : 0u;
            }
        }
        if (tid < T) {
            sidx[rank] = (u32)(kx & 0xFFFFFFFFull);
            const u32 pk = ~((u32)(kx >> 32));
            const u32 pb = (pk & 0x80000000u) ? (pk ^ 0x80000000u) : ~pk;
            sscore[rank] = __uint_as_float(pb);
        }
        for (int x = T + tid; x < TW * 64; x += NT_) sidx[x] = 0u;  // pad
    }
    __syncthreads();                     // keys dead; cmat may overlay now

    // --- stage candidate boxes (same op order as k_adj -> bit-identical) ---
    for (int t = tid; t < TW * 64; t += NT_) {
        const u32 idx = sidx[t];                 // pad rows use idx 0 (masked)
        const float4 bx = reinterpret_cast<const float4*>(boxes)[bN + idx];
        const float x1 = bx.x - bx.z * 0.5f;
        const float y1 = bx.y - bx.w * 0.5f;
        const float x2 = x1 + bx.z;
        const float y2 = y1 + bx.w;
        cbox[t] = make_float4(x1, y1, x2, y2);
    }
    __syncthreads();

    // --- build candidate-space adjacency matrix by direct IoU ---
    for (int r = wv; r < T; r += NWV_) {
        const float4 bi = cbox[r];               // broadcast read
        const float ai = (bi.z - bi.x) * (bi.w - bi.y);
        for (int g = 0; g < TW; ++g) {
            const float4 bj = cbox[g * 64 + lane];   // stride-1, conflict-free
            const float ajr = (bj.z - bj.x) * (bj.w - bj.y);
            const float ltx = fmaxf(bi.x, bj.x);
            const float lty = fmaxf(bi.y, bj.y);
            const float rbx = fminf(bi.z, bj.z);
            const float rby = fminf(bi.w, bj.w);
            const float whx = fmaxf(rbx - ltx, 0.0f);
            const float why = fmaxf(rby - lty, 0.0f);
            const float inter = whx * why;
            const float denom = (ai + ajr) - inter;
            const int pred = ((double)inter > MID * (double)denom) &&
                             (g * 64 + lane != r);   // exclude self-pair
            const u64 bm = __ballot(pred);
            if (lane == 0) ov.cmat[r][g] = bm;
        }
    }
    __syncthreads();

    // --- chunked greedy in candidate space ---
    u32 S = 0;                           // meaningful in wave 0
    const int NCH = (T + CH_ - 1) / CH_;
    for (int ch = 0; ch < NCH; ++ch) {
        const int c0 = ch * CH_;
        const int cn = min(CH_, T - c0);

        // wave 0: peel (parallel peeling == sequential greedy, R6-proven)
        if (wv == 0) {
            const u64 cmask = (cn >= 64) ? ~0ull : ((1ull << cn) - 1ull);
            u64 cv = valid[ch] & cmask;
            const u64 iv = (lane < cn) ? ov.cmat[c0 + lane][ch] : 0ull;
            const u64 below = (1ull << lane) - 1ull;
            u64 accept = 0ull;
            while (cv) {
                const int ok = ((cv >> lane) & 1ull) &&
                               ((iv & below & cv) == 0ull);
                const u64 ar = __ballot(ok);
                u64 sup = ok ? iv : 0ull;
#pragma unroll
                for (int off = 1; off < 64; off <<= 1)
                    sup |= __shfl_xor(sup, off);
                accept |= ar;
                cv &= ~(ar | sup);
            }
            if (lane == 0) s_accept = accept;
            if ((accept >> lane) & 1ull) {
                const u32 pos = S + (u32)__popcll(accept & below);
                slist[pos]  = sidx[c0 + lane];
                slistf[pos] = sscore[c0 + lane];
            }
            S += (u32)__popcll(accept);
        }
        __syncthreads();

        // all waves: suppress later words in parallel (one wave per word)
        const u64 ac = s_accept;
        const int g = ch + 1 + wv;
        if (g < TW && ac) {
            u64 sup = ((ac >> lane) & 1ull) ? ov.cmat[c0 + lane][g] : 0ull;
#pragma unroll
            for (int off = 1; off < 64; off <<= 1)
                sup |= __shfl_xor(sup, off);
            if (lane == 0) valid[g] &= ~sup;
        }
        __syncthreads();
    }
    if (wv == 0 && lane == 0) s_S = S;
    __syncthreads();

    // --- full-slice output (zeros past Sf; absorbs memset) ---
    const int Sf = (int)s_S;
    const float s = scales[b];
    for (int r = tid; r < N_; r += NT_) {
        float o0 = 0.f, o1 = 0.f, o2 = 0.f, o3 = 0.f, o4 = 0.f, mk = 0.f;
        if (r < Sf) {
            const int idx = (int)slist[r];
            const float4 bx = reinterpret_cast<const float4*>(boxes)[bN + idx];
            const float scx = bx.x * s, scy = bx.y * s;
            const float sw  = bx.z * s, sh  = bx.w * s;
            o0 = scx - 0.5f * sw;
            o1 = scy - 0.5f * sh;
            o2 = scx + 0.5f * sw;
            o3 = scy + 0.5f * sh;
            o4 = slistf[r];
            mk = 1.0f;
        }
        float* o = out + ((size_t)bc * N_ + r) * 5;
        o[0] = o0; o[1] = o1; o[2] = o2; o[3] = o3; o[4] = o4;
        out[(size_t)B_ * C_ * N_ * 5 + (size_t)bc * N_ + r] = mk;
    }
}

// ---------------------------------------------------------------------------
// K2 SLOW PATH (T > TMAX_ only; correctness insurance, trivially exits on
// this data): verbatim proven R5 kernel (N-space chunked greedy).
// ---------------------------------------------------------------------------
union OvT {
    u64 keys[NPAD_];
    u64 srows[2][CH_][NW_];
};

__global__ __launch_bounds__(NT_) void k_nms_slow(const u64* __restrict__ cand,
                                                  const u32* __restrict__ cnt,
                                                  const u64* __restrict__ adj,
                                                  const float* __restrict__ boxes,
                                                  const float* __restrict__ scales,
                                                  float* __restrict__ out) {
#pragma clang fp contract(off)
    __shared__ OvT ov;
    __shared__ u32 sidx[NPAD_];
    __shared__ float sscore[NPAD_];
    __shared__ u64 sintra[CH_];
    __shared__ u64 vmask[NW_];
    __shared__ u64 s_accept;
    __shared__ u32 slist[NPAD_];
    __shared__ float slistf[NPAD_];
    __shared__ u32 s_S;
    const int tid  = threadIdx.x;
    const int lane = tid & 63;
    const int wv   = tid >> 6;
    const int bc   = blockIdx.x;
    const int b    = bc / C_;
    const size_t bN = (size_t)b * N_;

    const int T  = (int)cnt[bc * 16];
    if (T <= TMAX_) return;                      // fast path handled
    const int TW = (T + 63) >> 6;
    for (int x = tid; x < TW * 64; x += NT_)
        ov.keys[x] = (x < T) ? cand[(size_t)bc * N_ + x] : ~0ull;
    if (tid < NW_) vmask[tid] = 0ull;
    __syncthreads();

    for (int xp = 0; xp * NT_ < T; ++xp) {
        const int x  = xp * NT_ + tid;
        const u64 kx = (x < T) ? ov.keys[x] : ~0ull;
        u32 rank = 0;
        for (int yb = 0; yb < TW; ++yb) {
            const u64 ky = ov.keys[yb * 64 + lane];
            const u32 kyl = (u32)ky, kyh = (u32)(ky >> 32);
#pragma unroll
            for (int l = 0; l < 64; ++l) {
                const u64 kb =
                    ((u64)(u32)__builtin_amdgcn_readlane((int)kyh, l) << 32)
                  |  (u64)(u32)__builtin_amdgcn_readlane((int)kyl, l);
                rank += (kb < kx) ? 1u : 0u;
            }
        }
        if (x < T) {
            const u32 i = (u32)(kx & 0xFFFFFFFFull);
            sidx[rank] = i;
            const u32 pk = ~((u32)(kx >> 32));
            const u32 pb = (pk & 0x80000000u) ? (pk ^ 0x80000000u) : ~pk;
            sscore[rank] = __uint_as_float(pb);
            atomicOr(&vmask[i >> 6], 1ull << (i & 63));
        }
    }
    __syncthreads();

#pragma unroll
    for (int rr = 0; rr < RPWG_; ++rr) {
        const int r = wv * RPWG_ + rr;
        const u32 idx = (r < T) ? sidx[r] : 0u;
        if (lane < NW_)
            ov.srows[0][r][lane] = adj[(bN + idx) * (size_t)NW_ + lane];
    }
    __syncthreads();

    u32 S = 0;
    const int NCH = (T + CH_ - 1) / CH_;
    for (int ch = 0; ch < NCH; ++ch) {
        const int cur = ch & 1, nxt = cur ^ 1;
        const int c0 = ch * CH_;
        const int cn = min(CH_, T - c0);
        const int havenext = (ch + 1 < NCH);

        u64 pre[RPWG_];
#pragma unroll
        for (int rr = 0; rr < RPWG_; ++rr) {
            const int r = wv * RPWG_ + rr;
            const int q = c0 + CH_ + r;
            const u32 idxn = (havenext && q < T) ? sidx[q] : 0u;
            pre[rr] = (havenext && lane < NW_)
                        ? adj[(bN + idxn) * (size_t)NW_ + lane] : 0ull;
        }
#pragma unroll
        for (int rr = 0; rr < RPWG_; ++rr) {
            const int r = wv * RPWG_ + rr;
            const u32 idxr = (c0 + r < T) ? sidx[c0 + r] : 0u;
            const u64 rj = ov.srows[cur][lane][idxr >> 6];
            const u64 ib = __ballot((lane < cn) && ((rj >> (idxr & 63)) & 1ull));
            if (lane == 0) sintra[r] = ib;
        }
        __syncthreads();

        if (wv == 0) {
            const u32 idxme = (c0 + lane < T) ? sidx[c0 + lane] : 0u;
            const u64 vm = vmask[idxme >> 6];
            u64 cv = __ballot((lane < cn) && ((vm >> (idxme & 63)) & 1ull));
            const u64 iv = sintra[lane];
            const u64 below = (1ull << lane) - 1ull;
            u64 accept = 0ull;
            while (cv) {
                const int ok = ((cv >> lane) & 1ull) &&
                               ((iv & below & cv) == 0ull);
                const u64 ar = __ballot(ok);
                u64 sup = ok ? iv : 0ull;
#pragma unroll
                for (int off = 1; off < 64; off <<= 1)
                    sup |= __shfl_xor(sup, off);
                accept |= ar;
                cv &= ~(ar | sup);
            }
            if (lane == 0) s_accept = accept;
            if ((accept >> lane) & 1ull) {
                const u32 pos = S + (u32)__popcll(accept & below);
                slist[pos]  = idxme;
                slistf[pos] = sscore[c0 + lane];
            }
            S += (u32)__popcll(accept);
        }
        __syncthreads();

        const u64 ac = s_accept;
        u64 acc = 0ull;
#pragma unroll
        for (int rr = 0; rr < RPWG_; ++rr) {
            const int r = wv * RPWG_ + rr;
            if ((ac >> r) & 1ull)
                acc |= ov.srows[cur][r][min(lane, NW_ - 1)];
        }
        if (lane < NW_ && acc)
            atomicAnd(&vmask[lane], ~acc);
        if (havenext) {
#pragma unroll
            for (int rr = 0; rr < RPWG_; ++rr) {
                const int r = wv * RPWG_ + rr;
                if (lane < NW_) ov.srows[nxt][r][lane] = pre[rr];
            }
        }
        __syncthreads();
    }
    if (wv == 0 && lane == 0) s_S = S;
    __syncthreads();

    const int Sf = (int)s_S;
    const float s = scales[b];
    for (int r = tid; r < N_; r += NT_) {
        float o0 = 0.f, o1 = 0.f, o2 = 0.f, o3 = 0.f, o4 = 0.f, mk = 0.f;
        if (r < Sf) {
            const int idx = (int)slist[r];
            const float4 bx = reinterpret_cast<const float4*>(boxes)[bN + idx];
            const float scx = bx.x * s, scy = bx.y * s;
            const float sw  = bx.z * s, sh  = bx.w * s;
            o0 = scx - 0.5f * sw;
            o1 = scy - 0.5f * sh;
            o2 = scx + 0.5f * sw;
            o3 = scy + 0.5f * sh;
            o4 = slistf[r];
            mk = 1.0f;
        }
        float* o = out + ((size_t)bc * N_ + r) * 5;
        o[0] = o0; o[1] = o1; o[2] = o2; o[3] = o3; o[4] = o4;
        out[(size_t)B_ * C_ * N_ * 5 + (size_t)bc * N_ + r] = mk;
    }
}

// ---------------------------------------------------------------------------
extern "C" void kernel_launch(void* const* d_in, const int* in_sizes, int n_in,
                              void* d_out, int out_size, void* d_ws, size_t ws_size,
                              hipStream_t stream) {
    const float* pro    = (const float*)d_in[0];   // (B,N,C)
    const float* con    = (const float*)d_in[1];   // (B,N,C)
    const float* boxes  = (const float*)d_in[2];   // (B,N,4)
    const float* scales = (const float*)d_in[3];   // (B,)
    const float* conf   = (const float*)d_in[4];   // (C,)

    char* ws = (char*)d_ws;
    u64* adj = (u64*)ws;                                   // B*N*NW u64  (6.57 MB)
    size_t off = (size_t)B_ * N_ * NW_ * sizeof(u64);
    u64* cand = (u64*)(ws + off);                          // B*C*N u64   (1.84 MB)
    off += (size_t)B_ * C_ * N_ * sizeof(u64);
    u32* cnt = (u32*)(ws + off);                           // B*C*16 u32  (padded)

    k_adj     <<<B_ * N_ / RPB_, 256, 0, stream>>>(boxes, adj);
    k_tr      <<<B_ * TPI_ / 4,  256, 0, stream>>>(adj, cnt);
    k_acon    <<<B_ * N_ / 4,    256, 0, stream>>>(adj, con, pro, conf, cand, cnt);
    k_nms_fast<<<B_ * C_,        NT_, 0, stream>>>(cand, cnt, boxes,
                                                   scales, (float*)d_out);
    k_nms_slow<<<B_ * C_,        NT_, 0, stream>>>(cand, cnt, adj, boxes,
                                                   scales, (float*)d_out);
}